// Round 1
// baseline (68.928 us; speedup 1.0000x reference)
//
#include <hip/hip_runtime.h>

#define BB 128
#define MM 256
#define NN (BB * MM)          // 32768 atoms
#define PP 2097152            // fixed pair-list length
#define RCF 5.0f
#define CCH 4                 // j-chunks per row
#define CHUNK (MM / CCH)      // 64
#define CNT_LEN (NN * CCH)    // 131072
#define NB1 (CNT_LEN / 256)   // 512

// ---------------------------------------------------------------------------
// Kernel 1: zero the whole output buffer (6P floats) and reduce per-dim min
// of all atom coords into minvec via atomicMin on float bits (coords >= 0).
// minvec must be pre-set to a huge value (memsetAsync 0x7f) before this runs.
// ---------------------------------------------------------------------------
__global__ void init_zero_min(const float* __restrict__ coord,
                              float* __restrict__ outF,
                              float* __restrict__ minvec) {
    const int tot4 = (6 * PP) / 4;  // float4 count = 3,145,728
    const int stride = gridDim.x * blockDim.x;
    float4 z = make_float4(0.f, 0.f, 0.f, 0.f);
    float4* o4 = reinterpret_cast<float4*>(outF);
    for (int t = blockIdx.x * blockDim.x + threadIdx.x; t < tot4; t += stride)
        o4[t] = z;

    int tid = blockIdx.x * blockDim.x + threadIdx.x;
    if (tid < NN) {  // blocks 0..127 fully covered -> wave-uniform
        float x = coord[3 * tid + 0];
        float y = coord[3 * tid + 1];
        float zc = coord[3 * tid + 2];
        #pragma unroll
        for (int off = 32; off > 0; off >>= 1) {
            x  = fminf(x,  __shfl_down(x,  off, 64));
            y  = fminf(y,  __shfl_down(y,  off, 64));
            zc = fminf(zc, __shfl_down(zc, off, 64));
        }
        if ((threadIdx.x & 63) == 0) {
            atomicMin(reinterpret_cast<int*>(&minvec[0]), __float_as_int(x));
            atomicMin(reinterpret_cast<int*>(&minvec[1]), __float_as_int(y));
            atomicMin(reinterpret_cast<int*>(&minvec[2]), __float_as_int(zc));
        }
    }
}

// ---------------------------------------------------------------------------
// Distance mask, replicating reference float32 arithmetic exactly:
// pos = coord - min (fp32 sub), diff = pos_j - pos_i,
// sq = ((dx*dx + dy*dy) + dz*dz) with NO fma contraction, dist = rn(sqrt(sq)),
// mask = (sq > 0) && (dist < 5).
// ---------------------------------------------------------------------------

// Kernel 2: per (row, chunk) pair counts. Block = (b, c), thread = i.
__global__ void __launch_bounds__(256)
count_k(const float* __restrict__ coord, const float* __restrict__ minvec,
        int* __restrict__ counts) {
    const int b = blockIdx.x / CCH;
    const int c = blockIdx.x % CCH;
    __shared__ float sx[CHUNK], sy[CHUNK], sz[CHUNK];
    const float mnx = minvec[0], mny = minvec[1], mnz = minvec[2];
    const int i = threadIdx.x;
    if (i < CHUNK) {
        int j = b * MM + c * CHUNK + i;
        sx[i] = __fsub_rn(coord[3 * j + 0], mnx);
        sy[i] = __fsub_rn(coord[3 * j + 1], mny);
        sz[i] = __fsub_rn(coord[3 * j + 2], mnz);
    }
    __syncthreads();
    const int gi = b * MM + i;
    const float pix = __fsub_rn(coord[3 * gi + 0], mnx);
    const float piy = __fsub_rn(coord[3 * gi + 1], mny);
    const float piz = __fsub_rn(coord[3 * gi + 2], mnz);
    int cnt = 0;
    for (int jj = 0; jj < CHUNK; ++jj) {
        float dx = __fsub_rn(sx[jj], pix);
        float dy = __fsub_rn(sy[jj], piy);
        float dz = __fsub_rn(sz[jj], piz);
        float sq = __fadd_rn(__fadd_rn(__fmul_rn(dx, dx), __fmul_rn(dy, dy)),
                             __fmul_rn(dz, dz));
        if (sq > 0.0f && __fsqrt_rn(sq) < RCF) cnt++;
    }
    counts[gi * CCH + c] = cnt;
}

// Kernel 3: per-256-block exclusive scan of counts (in place) + block sums.
__global__ void __launch_bounds__(256)
scan1_k(int* __restrict__ counts, int* __restrict__ blocksums) {
    __shared__ int tmp[256];
    const int tid = threadIdx.x;
    const int idx = blockIdx.x * 256 + tid;
    const int v = counts[idx];
    tmp[tid] = v;
    __syncthreads();
    #pragma unroll
    for (int off = 1; off < 256; off <<= 1) {
        int t = (tid >= off) ? tmp[tid - off] : 0;
        __syncthreads();
        tmp[tid] += t;
        __syncthreads();
    }
    counts[idx] = tmp[tid] - v;              // exclusive within block
    if (tid == 255) blocksums[blockIdx.x] = tmp[255];
}

// Kernel 4: single-block exclusive scan of the NB1 block sums (in place).
__global__ void __launch_bounds__(NB1)
scan2_k(int* __restrict__ bs) {
    __shared__ int tmp[NB1];
    const int tid = threadIdx.x;
    const int v = bs[tid];
    tmp[tid] = v;
    __syncthreads();
    #pragma unroll
    for (int off = 1; off < NB1; off <<= 1) {
        int t = (tid >= off) ? tmp[tid - off] : 0;
        __syncthreads();
        tmp[tid] += t;
        __syncthreads();
    }
    bs[tid] = tmp[tid] - v;                  // exclusive
}

// Kernel 5: recompute masks and write pairs at scanned global offsets.
// Output layout (floats): ind2 [0,2P) as {gi,gj}, d [2P,3P), df [3P,6P).
__global__ void __launch_bounds__(256)
write_k(const float* __restrict__ coord, const float* __restrict__ minvec,
        const int* __restrict__ counts, const int* __restrict__ bsum,
        float* __restrict__ outF) {
    const int b = blockIdx.x / CCH;
    const int c = blockIdx.x % CCH;
    __shared__ float sx[CHUNK], sy[CHUNK], sz[CHUNK];
    const float mnx = minvec[0], mny = minvec[1], mnz = minvec[2];
    const int i = threadIdx.x;
    if (i < CHUNK) {
        int j = b * MM + c * CHUNK + i;
        sx[i] = __fsub_rn(coord[3 * j + 0], mnx);
        sy[i] = __fsub_rn(coord[3 * j + 1], mny);
        sz[i] = __fsub_rn(coord[3 * j + 2], mnz);
    }
    __syncthreads();
    const int gi = b * MM + i;
    const float pix = __fsub_rn(coord[3 * gi + 0], mnx);
    const float piy = __fsub_rn(coord[3 * gi + 1], mny);
    const float piz = __fsub_rn(coord[3 * gi + 2], mnz);
    const int idx = gi * CCH + c;
    int p = counts[idx] + bsum[idx >> 8];
    const int gj0 = b * MM + c * CHUNK;
    for (int jj = 0; jj < CHUNK; ++jj) {
        float dx = __fsub_rn(sx[jj], pix);
        float dy = __fsub_rn(sy[jj], piy);
        float dz = __fsub_rn(sz[jj], piz);
        float sq = __fadd_rn(__fadd_rn(__fmul_rn(dx, dx), __fmul_rn(dy, dy)),
                             __fmul_rn(dz, dz));
        if (sq > 0.0f) {
            float dist = __fsqrt_rn(sq);
            if (dist < RCF) {
                if (p < PP) {
                    outF[2 * p + 0] = (float)gi;
                    outF[2 * p + 1] = (float)(gj0 + jj);
                    outF[2 * PP + p] = dist;
                    int dfb = 3 * PP + 3 * p;
                    outF[dfb + 0] = dx;
                    outF[dfb + 1] = dy;
                    outF[dfb + 2] = dz;
                }
                p++;
            }
        }
    }
}

extern "C" void kernel_launch(void* const* d_in, const int* in_sizes, int n_in,
                              void* d_out, int out_size, void* d_ws, size_t ws_size,
                              hipStream_t stream) {
    const float* coord = (const float*)d_in[0];
    // d_in[1] (ind_1) is structurally encoded; unused.
    float* outF = (float*)d_out;

    int*   counts    = (int*)d_ws;                               // 131072 ints
    int*   blocksums = (int*)((char*)d_ws + CNT_LEN * 4);        // 512 ints
    float* minvec    = (float*)((char*)d_ws + CNT_LEN * 4 + NB1 * 4);  // 3 floats

    // minvec := ~3.39e38 (0x7f7f7f7f), valid "+inf" for non-negative coords
    hipMemsetAsync(minvec, 0x7f, 3 * sizeof(float), stream);
    init_zero_min<<<512, 256, 0, stream>>>(coord, outF, minvec);
    count_k<<<BB * CCH, 256, 0, stream>>>(coord, minvec, counts);
    scan1_k<<<NB1, 256, 0, stream>>>(counts, blocksums);
    scan2_k<<<1, NB1, 0, stream>>>(blocksums);
    write_k<<<BB * CCH, 256, 0, stream>>>(coord, minvec, counts, blocksums, outF);
}

// Round 2
// 39.759 us; speedup vs baseline: 1.7337x; 1.7337x over previous
//
#include <hip/hip_runtime.h>

#define BB 128
#define MM 256
#define NN (BB * MM)          // 32768 atoms
#define PP 2097152            // fixed pair-list length
#define RCF 5.0f
#define NBLK 512              // (b, rowblock) blocks: 128 structures x 4 rowblocks
#define GTH (NBLK * 256)      // 131072 threads in count/write grids

// ---------------------------------------------------------------------------
// K1: per-block (256-atom) coordinate minima -> partials[128][3].
// Unconditional writes, so no initialization / atomics / memset needed.
// ---------------------------------------------------------------------------
__global__ void __launch_bounds__(256)
min_k(const float* __restrict__ coord, float* __restrict__ partials) {
    const int g = blockIdx.x * 256 + threadIdx.x;
    float x = coord[3 * g + 0];
    float y = coord[3 * g + 1];
    float z = coord[3 * g + 2];
    #pragma unroll
    for (int off = 32; off > 0; off >>= 1) {
        x = fminf(x, __shfl_xor(x, off, 64));
        y = fminf(y, __shfl_xor(y, off, 64));
        z = fminf(z, __shfl_xor(z, off, 64));
    }
    __shared__ float lx[4], ly[4], lz[4];
    const int w = threadIdx.x >> 6;
    if ((threadIdx.x & 63) == 0) { lx[w] = x; ly[w] = y; lz[w] = z; }
    __syncthreads();
    if (threadIdx.x == 0) {
        partials[3 * blockIdx.x + 0] = fminf(fminf(lx[0], lx[1]), fminf(lx[2], lx[3]));
        partials[3 * blockIdx.x + 1] = fminf(fminf(ly[0], ly[1]), fminf(ly[2], ly[3]));
        partials[3 * blockIdx.x + 2] = fminf(fminf(lz[0], lz[1]), fminf(lz[2], lz[3]));
    }
}

// Redundant register-only reduction of the 128 partial minima (every wave
// computes the same result via butterfly; L2-hit loads, no LDS/broadcast).
__device__ inline void reduce_min128(const float* __restrict__ partials,
                                     float& mnx, float& mny, float& mnz) {
    const int lane = threadIdx.x & 63;
    float x = fminf(partials[3 * lane + 0], partials[3 * (lane + 64) + 0]);
    float y = fminf(partials[3 * lane + 1], partials[3 * (lane + 64) + 1]);
    float z = fminf(partials[3 * lane + 2], partials[3 * (lane + 64) + 2]);
    #pragma unroll
    for (int off = 32; off > 0; off >>= 1) {
        x = fminf(x, __shfl_xor(x, off, 64));
        y = fminf(y, __shfl_xor(y, off, 64));
        z = fminf(z, __shfl_xor(z, off, 64));
    }
    mnx = x; mny = y; mnz = z;
}

// ---------------------------------------------------------------------------
// Block mapping (K2/K3): block b2 = b*4 + rblk owns rows i = rblk*64..+64 of
// structure b; thread t = i_loc*4 + c handles slot (row i_loc, j-chunk c).
// Global slot index b2*256 + t == ((b*256+i)*4 + c): lexicographic (b,i,j). ✓
// Reference fp32 arithmetic replicated exactly: pos = coord - min (rn sub),
// diff = pos_j - pos_i, sq = ((dx*dx+dy*dy)+dz*dz) no-FMA, dist = rn sqrt.
// ---------------------------------------------------------------------------

// K2: counts + block-local exclusive scan -> counts[GTH], bsums[NBLK].
__global__ void __launch_bounds__(256)
count_k(const float* __restrict__ coord, const float* __restrict__ partials,
        int* __restrict__ counts, int* __restrict__ bsums) {
    const int b2 = blockIdx.x;
    const int b = b2 >> 2, rblk = b2 & 3;
    float mnx, mny, mnz;
    reduce_min128(partials, mnx, mny, mnz);

    __shared__ float sx[256], sy[256], sz[256];
    __shared__ int tmp[256];
    const int t = threadIdx.x;
    const int ja = b * MM + t;
    sx[t] = __fsub_rn(coord[3 * ja + 0], mnx);
    sy[t] = __fsub_rn(coord[3 * ja + 1], mny);
    sz[t] = __fsub_rn(coord[3 * ja + 2], mnz);
    __syncthreads();

    const int i_loc = t >> 2, c = t & 3;
    const int row = rblk * 64 + i_loc;        // atom index within structure
    const float pix = sx[row], piy = sy[row], piz = sz[row];
    const int j0 = c * 64;
    int cnt = 0;
    for (int jj = 0; jj < 64; ++jj) {
        float dx = __fsub_rn(sx[j0 + jj], pix);
        float dy = __fsub_rn(sy[j0 + jj], piy);
        float dz = __fsub_rn(sz[j0 + jj], piz);
        float sq = __fadd_rn(__fadd_rn(__fmul_rn(dx, dx), __fmul_rn(dy, dy)),
                             __fmul_rn(dz, dz));
        if (sq > 0.0f && __fsqrt_rn(sq) < RCF) cnt++;
    }
    tmp[t] = cnt;
    __syncthreads();
    #pragma unroll
    for (int off = 1; off < 256; off <<= 1) {
        int v = (t >= off) ? tmp[t - off] : 0;
        __syncthreads();
        tmp[t] += v;
        __syncthreads();
    }
    counts[b2 * 256 + t] = tmp[t] - cnt;      // block-local exclusive
    if (t == 255) bsums[b2] = tmp[255];
}

// K3: redundant scan of bsums -> global base; write pairs; zero the tail.
// Output (floats): ind2 [0,2P) as {gi,gj}, d [2P,3P), df [3P,6P).
// Pair region [0,total) and tail [total,P) partition the buffer: every
// element written exactly once, no separate zero-fill pass.
__global__ void __launch_bounds__(256)
write_k(const float* __restrict__ coord, const float* __restrict__ partials,
        const int* __restrict__ counts, const int* __restrict__ bsums,
        float* __restrict__ outF) {
    const int b2 = blockIdx.x;
    const int b = b2 >> 2, rblk = b2 & 3;
    float mnx, mny, mnz;
    reduce_min128(partials, mnx, mny, mnz);

    __shared__ float sx[256], sy[256], sz[256];
    __shared__ int tmp[256];
    __shared__ int pre[NBLK];
    __shared__ int stot;
    const int t = threadIdx.x;
    const int ja = b * MM + t;
    sx[t] = __fsub_rn(coord[3 * ja + 0], mnx);
    sy[t] = __fsub_rn(coord[3 * ja + 1], mny);
    sz[t] = __fsub_rn(coord[3 * ja + 2], mnz);

    // redundant exclusive scan of 512 block sums (pairs of 2 per thread)
    const int v0 = bsums[2 * t], v1 = bsums[2 * t + 1];
    const int s01 = v0 + v1;
    tmp[t] = s01;
    __syncthreads();
    #pragma unroll
    for (int off = 1; off < 256; off <<= 1) {
        int v = (t >= off) ? tmp[t - off] : 0;
        __syncthreads();
        tmp[t] += v;
        __syncthreads();
    }
    const int excl = tmp[t] - s01;
    pre[2 * t] = excl;
    pre[2 * t + 1] = excl + v0;
    if (t == 255) stot = excl + s01;
    __syncthreads();

    const int base = pre[b2];
    const int total = stot;

    const int i_loc = t >> 2, c = t & 3;
    const int row = rblk * 64 + i_loc;
    const float pix = sx[row], piy = sy[row], piz = sz[row];
    const int gi = b * MM + row;
    const int gj0 = b * MM + c * 64;
    const int j0 = c * 64;
    int p = base + counts[b2 * 256 + t];
    for (int jj = 0; jj < 64; ++jj) {
        float dx = __fsub_rn(sx[j0 + jj], pix);
        float dy = __fsub_rn(sy[j0 + jj], piy);
        float dz = __fsub_rn(sz[j0 + jj], piz);
        float sq = __fadd_rn(__fadd_rn(__fmul_rn(dx, dx), __fmul_rn(dy, dy)),
                             __fmul_rn(dz, dz));
        if (sq > 0.0f) {
            float dist = __fsqrt_rn(sq);
            if (dist < RCF) {
                if (p < PP) {
                    outF[2 * p + 0] = (float)gi;
                    outF[2 * p + 1] = (float)(gj0 + jj);
                    outF[2 * PP + p] = dist;
                    const int dfb = 3 * PP + 3 * p;
                    outF[dfb + 0] = dx;
                    outF[dfb + 1] = dy;
                    outF[dfb + 2] = dz;
                }
                p++;
            }
        }
    }

    // tail zeroing (disjoint from pair region; grid-strided, coalesced)
    const int g = b2 * 256 + t;
    for (int k = 2 * total + g;     k < 2 * PP; k += GTH) outF[k] = 0.0f;
    for (int k = 2 * PP + total + g; k < 3 * PP; k += GTH) outF[k] = 0.0f;
    for (int k = 3 * PP + 3 * total + g; k < 6 * PP; k += GTH) outF[k] = 0.0f;
}

extern "C" void kernel_launch(void* const* d_in, const int* in_sizes, int n_in,
                              void* d_out, int out_size, void* d_ws, size_t ws_size,
                              hipStream_t stream) {
    const float* coord = (const float*)d_in[0];
    // d_in[1] (ind_1) is structurally encoded (B contiguous blocks of M); unused.
    float* outF = (float*)d_out;

    int*   counts    = (int*)d_ws;                                // 131072 ints
    int*   bsums     = (int*)((char*)d_ws + GTH * 4);             // 512 ints
    float* partials  = (float*)((char*)d_ws + GTH * 4 + NBLK * 4);// 384 floats

    min_k  <<<128,  256, 0, stream>>>(coord, partials);
    count_k<<<NBLK, 256, 0, stream>>>(coord, partials, counts, bsums);
    write_k<<<NBLK, 256, 0, stream>>>(coord, partials, counts, bsums, outF);
}